// Round 6
// baseline (543.884 us; speedup 1.0000x reference)
//
#include <hip/hip_runtime.h>

#define N_NODES 100000
#define SHIFT 9
#define BNODES 512                               // nodes per dst bucket
#define NB 196                                   // ceil(N_NODES/BNODES)
#define TRASH BNODES
#define DUMMY (TRASH << 17)                      // pad record: src=0, dl=512
#define SPLIT 8                                  // edge slices per bucket (agg)
#define GRID 512
#define BS 256

// ---------------------------------------------------------------------------
// GCN 2-layer, algebraically refactored (aggregation in 2-dim feature space):
//   out = Â relu( (Â x) W1^T + b1 ) W2^T + b2 ,  Â = D^-1/2 (A+I) D^-1/2
// Single persistent kernel with a hand-rolled grid barrier (R5's cooperative
// launch never executed). Barrier: device-scope atomic counter; writers
// __threadfence() (L2 writeback) before arriving, waiters __threadfence()
// (L2/L1 invalidate) after the spin -> cross-XCD visibility per G16.
// 512 blocks @ __launch_bounds__(256,4): needs 2 blocks/CU, HW guarantees 4.
// ---------------------------------------------------------------------------

__device__ __forceinline__ void gbar(int* cnt, int target) {
    __syncthreads();                 // also drains this block's stores (vmcnt0)
    if (threadIdx.x == 0) {
        __threadfence();             // release: push XCD-L2 dirty lines to LLC
        __hip_atomic_fetch_add(cnt, 1, __ATOMIC_RELAXED, __HIP_MEMORY_SCOPE_AGENT);
        while (__hip_atomic_load(cnt, __ATOMIC_RELAXED, __HIP_MEMORY_SCOPE_AGENT) < target)
            __builtin_amdgcn_s_sleep(8);
        __threadfence();             // acquire: invalidate stale L1/L2 lines
    }
    __syncthreads();
}

__global__ __launch_bounds__(BS, 4) void k_fused(
    const float* __restrict__ x,
    const int* __restrict__ src,
    const int* __restrict__ dst,
    const float* __restrict__ W1,
    const float* __restrict__ b1,
    const float* __restrict__ W2,
    const float* __restrict__ b2,
    int* bar, int* counts, int* sorted,
    float* dinv, float2* u, float2* acc1,
    float2* v, float2* acc2,
    float2* out, int e)
{
    __shared__ int   s_off[NB + 1];          // bucket offsets, alive all kernel
    __shared__ int   s_base[NB];             // this block's claimed base per bin
    __shared__ int   s_hist[2 * NB];         // hist replicas / rank counters
    __shared__ int   s_cnt[BNODES + 1];      // scan scratch, then degree tile
    __shared__ float s_ax[BNODES + 1], s_ay[BNODES + 1];
    __shared__ float sW1[128], sb1[64], sW2[128];

    const int t = threadIdx.x;
    const int bid = blockIdx.x;
    const int ce = (((e + GRID - 1) / GRID) + 3) & ~3;
    const int s0 = bid * ce;
    const int en = min(s0 + ce, e);

    // ---- P1: local histogram (2 LDS replicas) + atomic range claim ----
    for (int i = t; i < 2 * NB; i += BS) s_hist[i] = 0;
    __syncthreads();
    int* myh = s_hist + ((t >> 7) ? NB : 0);
    if (s0 < e) {
        for (int i = s0 + 4 * t; i + 3 < en; i += 4 * BS) {
            int4 d4 = *(const int4*)(dst + i);
            atomicAdd(&myh[d4.x >> SHIFT], 1);
            atomicAdd(&myh[d4.y >> SHIFT], 1);
            atomicAdd(&myh[d4.z >> SHIFT], 1);
            atomicAdd(&myh[d4.w >> SHIFT], 1);
        }
        int tb = en & ~3;
        if (tb >= s0 && t < en - tb) atomicAdd(&myh[dst[tb + t] >> SHIFT], 1);
    }
    __syncthreads();
    for (int i = t; i < NB; i += BS) {
        int c = s_hist[i] + s_hist[NB + i];
        s_base[i] = c ? atomicAdd(&counts[i], c) : 0;
    }
    gbar(bar, 1 * GRID);

    // ---- P2: every block scans the x4-padded final counts locally ----
    int cfin = (t < NB) ? counts[t] : 0;
    int pc = (cfin + 3) & ~3;
    s_cnt[t] = pc;
    __syncthreads();
    for (int off = 1; off < 256; off <<= 1) {
        int w = (t >= off) ? s_cnt[t - off] : 0;
        __syncthreads();
        s_cnt[t] += w;
        __syncthreads();
    }
    if (t < NB) s_off[t + 1] = s_cnt[t];
    if (t == 0) s_off[0] = 0;
    __syncthreads();

    // pads (block 0 only; <=3 per bucket)
    if (bid == 0 && t < NB) {
        int p0 = s_off[t] + cfin, p1 = s_off[t + 1];
        for (int i = p0; i < p1; ++i) sorted[i] = DUMMY;
    }

    // ---- P3: place (rank counters = s_hist[0..NB)) ----
    for (int i = t; i < NB; i += BS) s_hist[i] = 0;
    __syncthreads();
    if (s0 < e) {
        for (int i = s0 + 4 * t; i + 3 < en; i += 4 * BS) {
            int4 s4 = *(const int4*)(src + i);
            int4 d4 = *(const int4*)(dst + i);
            int bin, r;
            bin = d4.x >> SHIFT; r = atomicAdd(&s_hist[bin], 1);
            sorted[s_off[bin] + s_base[bin] + r] = s4.x | ((d4.x & (BNODES - 1)) << 17);
            bin = d4.y >> SHIFT; r = atomicAdd(&s_hist[bin], 1);
            sorted[s_off[bin] + s_base[bin] + r] = s4.y | ((d4.y & (BNODES - 1)) << 17);
            bin = d4.z >> SHIFT; r = atomicAdd(&s_hist[bin], 1);
            sorted[s_off[bin] + s_base[bin] + r] = s4.z | ((d4.z & (BNODES - 1)) << 17);
            bin = d4.w >> SHIFT; r = atomicAdd(&s_hist[bin], 1);
            sorted[s_off[bin] + s_base[bin] + r] = s4.w | ((d4.w & (BNODES - 1)) << 17);
        }
        int tb = en & ~3;
        if (tb >= s0 && t < en - tb) {
            int d = dst[tb + t];
            int bin = d >> SHIFT;
            int r = atomicAdd(&s_hist[bin], 1);
            sorted[s_off[bin] + s_base[bin] + r] = src[tb + t] | ((d & (BNODES - 1)) << 17);
        }
    }
    gbar(bar, 2 * GRID);

    // ---- P4: per-bucket degree + prep (blocks 0..NB-1) ----
    if (bid < NB) {
        for (int i = t; i <= BNODES; i += BS) s_cnt[i] = 0;
        __syncthreads();
        int s = s_off[bid], e2 = s_off[bid + 1];
        for (int i = s + 4 * t; i + 3 < e2; i += 4 * BS) {
            int4 p = *(const int4*)(sorted + i);
            atomicAdd(&s_cnt[((unsigned)p.x) >> 17], 1);
            atomicAdd(&s_cnt[((unsigned)p.y) >> 17], 1);
            atomicAdd(&s_cnt[((unsigned)p.z) >> 17], 1);
            atomicAdd(&s_cnt[((unsigned)p.w) >> 17], 1);
        }
        __syncthreads();
        for (int i = t; i < BNODES; i += BS) {
            int node = bid * BNODES + i;
            if (node < N_NODES) {
                float dv = rsqrtf((float)(s_cnt[i] + 1));   // +1 self-loop
                dinv[node] = dv;
                float2 xv = ((const float2*)x)[node];
                float2 uu = make_float2(dv * xv.x, dv * xv.y);
                u[node] = uu;
                acc1[node] = uu;  // self term
            }
        }
    }
    gbar(bar, 3 * GRID);

    // ---- P5: agg1 (LDS tile per bucket slice, contiguous atomic flush) ----
    for (int vi = bid; vi < NB * SPLIT; vi += GRID) {
        int b = vi / SPLIT, k = vi - b * SPLIT;
        int s = s_off[b], e2 = s_off[b + 1];
        int ch = ((((e2 - s) + SPLIT - 1) / SPLIT) + 3) & ~3;
        int vs = s + k * ch;
        int ve = min(vs + ch, e2);
        if (vs >= ve) continue;  // block-uniform
        for (int i = t; i <= BNODES; i += BS) { s_ax[i] = 0.f; s_ay[i] = 0.f; }
        __syncthreads();
        for (int i = vs + 4 * t; i + 3 < ve; i += 4 * BS) {
            int4 p = *(const int4*)(sorted + i);
            float2 g0 = u[p.x & 0x1FFFF];
            float2 g1 = u[p.y & 0x1FFFF];
            float2 g2 = u[p.z & 0x1FFFF];
            float2 g3 = u[p.w & 0x1FFFF];
            int d0 = ((unsigned)p.x) >> 17, d1 = ((unsigned)p.y) >> 17;
            int d2 = ((unsigned)p.z) >> 17, d3 = ((unsigned)p.w) >> 17;
            atomicAdd(&s_ax[d0], g0.x); atomicAdd(&s_ay[d0], g0.y);
            atomicAdd(&s_ax[d1], g1.x); atomicAdd(&s_ay[d1], g1.y);
            atomicAdd(&s_ax[d2], g2.x); atomicAdd(&s_ay[d2], g2.y);
            atomicAdd(&s_ax[d3], g3.x); atomicAdd(&s_ay[d3], g3.y);
        }
        __syncthreads();
        for (int i = t; i < BNODES; i += BS) {
            int node = b * BNODES + i;
            if (node < N_NODES) {
                float vx = s_ax[i], vy = s_ay[i];
                if (vx != 0.f || vy != 0.f) {
                    atomicAdd(&((float*)acc1)[2 * node], vx);
                    atomicAdd(&((float*)acc1)[2 * node + 1], vy);
                }
            }
        }
        __syncthreads();
    }
    gbar(bar, 4 * GRID);

    // ---- P6: per-node MLP (64-dim hidden entirely in registers) ----
    if (t < 128) { sW1[t] = W1[t]; sW2[t] = W2[t]; }
    else if (t < 192) sb1[t - 128] = b1[t - 128];
    __syncthreads();
    for (int i = bid * BS + t; i < N_NODES; i += GRID * BS) {
        float dv = dinv[i];
        float2 a2 = acc1[i];
        float a0 = dv * a2.x, a1 = dv * a2.y;
        float y0 = 0.f, y1 = 0.f;
#pragma unroll
        for (int j = 0; j < 64; ++j) {
            float h = fmaxf(fmaf(sW1[2 * j], a0,
                            fmaf(sW1[2 * j + 1], a1, sb1[j])), 0.f);
            y0 = fmaf(sW2[j], h, y0);        // W2[0][j]
            y1 = fmaf(sW2[64 + j], h, y1);   // W2[1][j]
        }
        float2 vv = make_float2(dv * y0, dv * y1);
        v[i] = vv;
        acc2[i] = vv;  // self term
    }
    gbar(bar, 5 * GRID);

    // ---- P7: agg2 ----
    for (int vi = bid; vi < NB * SPLIT; vi += GRID) {
        int b = vi / SPLIT, k = vi - b * SPLIT;
        int s = s_off[b], e2 = s_off[b + 1];
        int ch = ((((e2 - s) + SPLIT - 1) / SPLIT) + 3) & ~3;
        int vs = s + k * ch;
        int ve = min(vs + ch, e2);
        if (vs >= ve) continue;
        for (int i = t; i <= BNODES; i += BS) { s_ax[i] = 0.f; s_ay[i] = 0.f; }
        __syncthreads();
        for (int i = vs + 4 * t; i + 3 < ve; i += 4 * BS) {
            int4 p = *(const int4*)(sorted + i);
            float2 g0 = v[p.x & 0x1FFFF];
            float2 g1 = v[p.y & 0x1FFFF];
            float2 g2 = v[p.z & 0x1FFFF];
            float2 g3 = v[p.w & 0x1FFFF];
            int d0 = ((unsigned)p.x) >> 17, d1 = ((unsigned)p.y) >> 17;
            int d2 = ((unsigned)p.z) >> 17, d3 = ((unsigned)p.w) >> 17;
            atomicAdd(&s_ax[d0], g0.x); atomicAdd(&s_ay[d0], g0.y);
            atomicAdd(&s_ax[d1], g1.x); atomicAdd(&s_ay[d1], g1.y);
            atomicAdd(&s_ax[d2], g2.x); atomicAdd(&s_ay[d2], g2.y);
            atomicAdd(&s_ax[d3], g3.x); atomicAdd(&s_ay[d3], g3.y);
        }
        __syncthreads();
        for (int i = t; i < BNODES; i += BS) {
            int node = b * BNODES + i;
            if (node < N_NODES) {
                float vx = s_ax[i], vy = s_ay[i];
                if (vx != 0.f || vy != 0.f) {
                    atomicAdd(&((float*)acc2)[2 * node], vx);
                    atomicAdd(&((float*)acc2)[2 * node + 1], vy);
                }
            }
        }
        __syncthreads();
    }
    gbar(bar, 6 * GRID);

    // ---- P8: out = dinv*acc2 + b2 ----
    float bb0 = b2[0], bb1 = b2[1];
    for (int i = bid * BS + t; i < N_NODES; i += GRID * BS) {
        float dv = dinv[i];
        float2 s2 = acc2[i];
        out[i] = make_float2(fmaf(dv, s2.x, bb0), fmaf(dv, s2.y, bb1));
    }
}

extern "C" void kernel_launch(void* const* d_in, const int* in_sizes, int n_in,
                              void* d_out, int out_size, void* d_ws, size_t ws_size,
                              hipStream_t stream) {
    const float* x  = (const float*)d_in[0];
    const int* ei   = (const int*)d_in[1];   // [2,E]: src row then dst row
    const float* W1 = (const float*)d_in[2];
    const float* b1 = (const float*)d_in[3];
    const float* W2 = (const float*)d_in[4];
    const float* b2 = (const float*)d_in[5];

    int e = in_sizes[1] / 2;
    const int* src = ei;
    const int* dst = ei + e;

    // ws layout (4B units): bar[4] | counts[NB] | pad | sorted[e+4NB] |
    //                       dinv[N] | u[2N] | acc1[2N] | v[2N] | acc2[2N]
    int* ws     = (int*)d_ws;
    int* bar    = ws;
    int* counts = ws + 4;
    int* sorted = ws + ((4 + NB + 3) & ~3);        // 16B-aligned
    int cap     = (e + 4 * NB + 3) & ~3;
    float* dinv = (float*)(sorted + cap);
    float2* u    = (float2*)(dinv + N_NODES);
    float2* acc1 = u + N_NODES;
    float2* v    = acc1 + N_NODES;
    float2* acc2 = v + N_NODES;
    float2* outp = (float2*)d_out;

    hipMemsetAsync(bar, 0, (4 + NB) * sizeof(int), stream);

    k_fused<<<GRID, BS, 0, stream>>>(x, src, dst, W1, b1, W2, b2,
                                     bar, counts, sorted, dinv, u, acc1,
                                     v, acc2, outp, e);
}

// Round 7
// 193.521 us; speedup vs baseline: 2.8105x; 2.8105x over previous
//
#include <hip/hip_runtime.h>

#define N_NODES 100000
#define SHIFT 9
#define BNODES 512                              // nodes per dst bucket
#define NB 196                                  // ceil(N_NODES/BNODES)
#define CAP 18432                               // per-bucket slots; mean 16327, +16sigma; %4==0
#define SPLIT 8                                 // edge slices per bucket (agg)
#define TILE 4096                               // edges per sort block
#define SB 256
#define NBK ((N_NODES + 255) / 256)

// ---------------------------------------------------------------------------
// GCN 2-layer, algebraically refactored (aggregation in 2-dim feature space):
//   out = Â relu( (Â x) W1^T + b1 ) W2^T + b2 ,  Â = D^-1/2 (A+I) D^-1/2
// R6 lesson: grid barriers cost >> kernel boundaries on gfx950 (fence = L2
// writeback per block). Multi-kernel, but single-pass bucketed sort:
//   k_sort: per 4096-edge tile -> LDS hist/scan -> one global claim per bin
//           -> LDS-staged reorder -> COALESCED run writes into over-allocated
//           per-bucket storage (CAP slots/bucket; lengths in claim[]).
//   k_degprep: per-bucket LDS degree count + dinv/u/acc1 (fused).
//   k_agg: LDS tile accumulate per bucket slice, contiguous atomic flush.
//   k_mlp: 64-dim hidden layer entirely in registers.
// Record: src (17b) | dst_local (9b) << 17.
// ---------------------------------------------------------------------------

__global__ __launch_bounds__(SB) void k_sort(const int* __restrict__ src,
                                             const int* __restrict__ dst,
                                             int* claim, int* sg, int e) {
    __shared__ int hist[NB];
    __shared__ int cnt[SB];                 // scan buffer, then rank counters
    __shared__ int start[NB];               // tile-local exclusive starts
    __shared__ int runbase[NB];             // claimed global run base per bin
    __shared__ int stage[TILE];
    __shared__ unsigned char binmap[TILE];

    const int t = threadIdx.x;
    const int base = blockIdx.x * TILE;
    const int n = min(TILE, e - base);

    for (int i = t; i < NB; i += SB) hist[i] = 0;
    __syncthreads();

    int recs[16];
    int bins[16];
#pragma unroll
    for (int k = 0; k < 4; ++k) {
        int idx = base + (k * SB + t) * 4;
        if (idx + 3 < e) {
            int4 s4 = *(const int4*)(src + idx);
            int4 d4 = *(const int4*)(dst + idx);
            int ss[4] = {s4.x, s4.y, s4.z, s4.w};
            int dd[4] = {d4.x, d4.y, d4.z, d4.w};
#pragma unroll
            for (int j = 0; j < 4; ++j) {
                int b = dd[j] >> SHIFT;
                bins[4 * k + j] = b;
                recs[4 * k + j] = ss[j] | ((dd[j] & (BNODES - 1)) << 17);
                atomicAdd(&hist[b], 1);
            }
        } else {
#pragma unroll
            for (int j = 0; j < 4; ++j) {
                int i2 = idx + j;
                if (i2 < e) {
                    int d = dst[i2];
                    int b = d >> SHIFT;
                    bins[4 * k + j] = b;
                    recs[4 * k + j] = src[i2] | ((d & (BNODES - 1)) << 17);
                    atomicAdd(&hist[b], 1);
                } else {
                    bins[4 * k + j] = -1;
                }
            }
        }
    }
    __syncthreads();

    // Hillis-Steele inclusive scan of hist over 256 slots
    cnt[t] = (t < NB) ? hist[t] : 0;
    __syncthreads();
    for (int off = 1; off < SB; off <<= 1) {
        int w = (t >= off) ? cnt[t - off] : 0;
        __syncthreads();
        cnt[t] += w;
        __syncthreads();
    }
    if (t < NB) {
        int excl = cnt[t] - hist[t];
        start[t] = excl;
        cnt[t] = excl;                       // rank counters (own slot only)
        int c = hist[t];
        runbase[t] = c ? atomicAdd(&claim[t], c) : 0;
    }
    __syncthreads();

    // rank + stage
#pragma unroll
    for (int m = 0; m < 16; ++m) {
        int b = bins[m];
        if (b >= 0) {
            int pos = atomicAdd(&cnt[b], 1);
            stage[pos] = recs[m];
            binmap[pos] = (unsigned char)b;
        }
    }
    __syncthreads();

    // coalesced copy-out: consecutive staged slots -> consecutive run slots
    for (int i = t; i < n; i += SB) {
        int b = binmap[i];
        sg[b * CAP + runbase[b] + (i - start[b])] = stage[i];
    }
}

// per bucket: LDS degree count + dinv = rsqrt(deg+1), u = dinv*x, acc1 = u
__global__ __launch_bounds__(1024) void k_degprep(const int* __restrict__ claim,
                                                  const int* __restrict__ sg,
                                                  const float* __restrict__ x,
                                                  float* dinv, float2* u,
                                                  float2* acc1) {
    __shared__ int cnt[BNODES];
    int t = threadIdx.x;
    if (t < BNODES) cnt[t] = 0;
    __syncthreads();
    int b = blockIdx.x;
    const int* p = sg + b * CAP;
    int len = claim[b];
    int tb = len & ~3;
    for (int i = 4 * t; i < tb; i += 4 * 1024) {
        int4 r = *(const int4*)(p + i);
        atomicAdd(&cnt[((unsigned)r.x) >> 17], 1);
        atomicAdd(&cnt[((unsigned)r.y) >> 17], 1);
        atomicAdd(&cnt[((unsigned)r.z) >> 17], 1);
        atomicAdd(&cnt[((unsigned)r.w) >> 17], 1);
    }
    if (t < len - tb) atomicAdd(&cnt[((unsigned)p[tb + t]) >> 17], 1);
    __syncthreads();
    if (t < BNODES) {
        int node = b * BNODES + t;
        if (node < N_NODES) {
            float dv = rsqrtf((float)(cnt[t] + 1));   // +1 self-loop
            dinv[node] = dv;
            float2 xv = ((const float2*)x)[node];
            float2 uu = make_float2(dv * xv.x, dv * xv.y);
            u[node] = uu;
            acc1[node] = uu;                           // self term
        }
    }
}

// bucket-slice aggregation: LDS tile accumulate, contiguous atomic flush
__global__ __launch_bounds__(SB) void k_agg(const int* __restrict__ claim,
                                            const int* __restrict__ sg,
                                            const float2* __restrict__ g,
                                            float* acc) {
    __shared__ float ax[BNODES], ay[BNODES];
    int t = threadIdx.x;
    int b = blockIdx.x / SPLIT, k = blockIdx.x % SPLIT;
    for (int i = t; i < BNODES; i += SB) { ax[i] = 0.f; ay[i] = 0.f; }
    __syncthreads();
    int len = claim[b];
    int ch = (((len + SPLIT - 1) / SPLIT) + 3) & ~3;
    int vs = k * ch;
    int ve = min(vs + ch, len);
    const int* p = sg + b * CAP;
    if (vs < ve) {
        int tb = vs + ((ve - vs) & ~3);
        for (int i = vs + 4 * t; i < tb; i += 4 * SB) {
            int4 r = *(const int4*)(p + i);
            float2 g0 = g[r.x & 0x1FFFF];
            float2 g1 = g[r.y & 0x1FFFF];
            float2 g2 = g[r.z & 0x1FFFF];
            float2 g3 = g[r.w & 0x1FFFF];
            int d0 = ((unsigned)r.x) >> 17, d1 = ((unsigned)r.y) >> 17;
            int d2 = ((unsigned)r.z) >> 17, d3 = ((unsigned)r.w) >> 17;
            atomicAdd(&ax[d0], g0.x); atomicAdd(&ay[d0], g0.y);
            atomicAdd(&ax[d1], g1.x); atomicAdd(&ay[d1], g1.y);
            atomicAdd(&ax[d2], g2.x); atomicAdd(&ay[d2], g2.y);
            atomicAdd(&ax[d3], g3.x); atomicAdd(&ay[d3], g3.y);
        }
        if (t < ve - tb) {
            int r = p[tb + t];
            float2 gg = g[r & 0x1FFFF];
            int dl = ((unsigned)r) >> 17;
            atomicAdd(&ax[dl], gg.x); atomicAdd(&ay[dl], gg.y);
        }
    }
    __syncthreads();
    for (int i = t; i < BNODES; i += SB) {
        int node = b * BNODES + i;
        if (node < N_NODES) {
            float vx = ax[i], vy = ay[i];
            if (vx != 0.f || vy != 0.f) {
                atomicAdd(&acc[2 * node], vx);
                atomicAdd(&acc[2 * node + 1], vy);
            }
        }
    }
}

// node: a = dinv*acc1; h = relu(W1 a + b1) in regs; v = dinv*(W2 h); acc2 = v
__global__ __launch_bounds__(256) void k_mlp(const float* __restrict__ dinv,
                                             const float2* acc1,
                                             const float* __restrict__ W1,
                                             const float* __restrict__ b1,
                                             const float* __restrict__ W2,
                                             float2* v, float2* acc2) {
    __shared__ float sW1[128], sb1[64], sW2[128];
    int t = threadIdx.x;
    if (t < 128) { sW1[t] = W1[t]; sW2[t] = W2[t]; }
    else if (t < 192) sb1[t - 128] = b1[t - 128];
    __syncthreads();
    int i = blockIdx.x * 256 + t;
    if (i < N_NODES) {
        float dv = dinv[i];
        float2 a2 = acc1[i];
        float a0 = dv * a2.x, a1 = dv * a2.y;
        float y0 = 0.f, y1 = 0.f;
#pragma unroll
        for (int j = 0; j < 64; ++j) {
            float h = fmaxf(fmaf(sW1[2 * j], a0,
                            fmaf(sW1[2 * j + 1], a1, sb1[j])), 0.f);
            y0 = fmaf(sW2[j], h, y0);        // W2[0][j]
            y1 = fmaf(sW2[64 + j], h, y1);   // W2[1][j]
        }
        float2 vv = make_float2(dv * y0, dv * y1);
        v[i] = vv;                           // aliases u (dead after agg1)
        acc2[i] = vv;                        // aliases acc1 (per-element safe)
    }
}

__global__ __launch_bounds__(256) void k_out(const float* __restrict__ dinv,
                                             const float2* __restrict__ acc2,
                                             const float* __restrict__ b2,
                                             float2* out) {
    int i = blockIdx.x * 256 + threadIdx.x;
    if (i < N_NODES) {
        float dv = dinv[i];
        float2 s = acc2[i];
        out[i] = make_float2(fmaf(dv, s.x, b2[0]), fmaf(dv, s.y, b2[1]));
    }
}

extern "C" void kernel_launch(void* const* d_in, const int* in_sizes, int n_in,
                              void* d_out, int out_size, void* d_ws, size_t ws_size,
                              hipStream_t stream) {
    const float* x  = (const float*)d_in[0];
    const int* ei   = (const int*)d_in[1];   // [2,E]: src row then dst row
    const float* W1 = (const float*)d_in[2];
    const float* b1 = (const float*)d_in[3];
    const float* W2 = (const float*)d_in[4];
    const float* b2 = (const float*)d_in[5];

    int e = in_sizes[1] / 2;
    const int* src = ei;
    const int* dst = ei + e;

    // ws layout (4B units): claim[NB(=196,%4==0)] | sg[NB*CAP] | dinv[N] |
    //                       u[2N] (v aliases) | acc1[2N] (acc2 aliases)
    int* ws      = (int*)d_ws;
    int* claim   = ws;
    int* sg      = ws + NB;                       // 16B-aligned (196%4==0)
    float* dinv  = (float*)(sg + NB * CAP);
    float2* u    = (float2*)(dinv + N_NODES);
    float2* acc1 = u + N_NODES;
    float2* v    = u;                             // alias: u dead after agg1
    float2* acc2 = acc1;                          // alias: per-element overwrite
    float2* outp = (float2*)d_out;

    hipMemsetAsync(claim, 0, NB * sizeof(int), stream);

    k_sort   <<<(e + TILE - 1) / TILE, SB, 0, stream>>>(src, dst, claim, sg, e);
    k_degprep<<<NB, 1024, 0, stream>>>(claim, sg, x, dinv, u, acc1);
    k_agg    <<<NB * SPLIT, SB, 0, stream>>>(claim, sg, u, (float*)acc1);
    k_mlp    <<<NBK, 256, 0, stream>>>(dinv, acc1, W1, b1, W2, v, acc2);
    k_agg    <<<NB * SPLIT, SB, 0, stream>>>(claim, sg, v, (float*)acc2);
    k_out    <<<NBK, 256, 0, stream>>>(dinv, acc2, b2, outp);
}

// Round 8
// 165.963 us; speedup vs baseline: 3.2771x; 1.1660x over previous
//
#include <hip/hip_runtime.h>

#define N_NODES 100000
#define SHIFT 9
#define BNODES 512                              // nodes per dst bucket
#define NB 196                                  // ceil(N_NODES/BNODES)
#define CAP 18432                               // slots/bucket; mean 16327, +16sigma; %4==0
#define TILE 4096                               // edges per sort block
#define SB 256

// ---------------------------------------------------------------------------
// GCN 2-layer, algebraically refactored (aggregation in 2-dim feature space):
//   out = Â relu( (Â x) W1^T + b1 ) W2^T + b2 ,  Â = D^-1/2 (A+I) D^-1/2
// R7 analysis: ~22.6M LDS atomics (~100us) were the hidden bottleneck.
// New plan: two-level sort to FULL per-node order, then atomic-free
// aggregation:
//   k_sort:   tile -> LDS hist/scan/stage -> coalesced runs per 512-node
//             bucket (claim[] = lengths).         [6.4M LDS atomics]
//   k_refine: per bucket counting-sort by dst_local (scatter stays inside the
//             block's own 64KB L2 region) + per-node beg/end + dinv + u=dinv*x
//             (degree == segment length).         [6.4M LDS atomics]
//   k_agg1:   thread-per-node segment sum of u[src] (ZERO atomics) fused with
//             the full 64-dim register MLP -> v.
//   k_agg2:   segment sum of v[src] fused with bias -> out.
// 5 dispatches, no global atomic flushes, no acc arrays.
// ---------------------------------------------------------------------------

__global__ __launch_bounds__(SB) void k_sort(const int* __restrict__ src,
                                             const int* __restrict__ dst,
                                             int* claim, int* sg, int e) {
    __shared__ int hist[NB];
    __shared__ int cnt[SB];                 // scan buffer, then rank counters
    __shared__ int start[NB];               // tile-local exclusive starts
    __shared__ int runbase[NB];             // claimed global run base per bin
    __shared__ int stage[TILE];
    __shared__ unsigned char binmap[TILE];

    const int t = threadIdx.x;
    const int base = blockIdx.x * TILE;
    const int n = min(TILE, e - base);

    for (int i = t; i < NB; i += SB) hist[i] = 0;
    __syncthreads();

    int recs[16];
    int bins[16];
#pragma unroll
    for (int k = 0; k < 4; ++k) {
        int idx = base + (k * SB + t) * 4;
        if (idx + 3 < e) {
            int4 s4 = *(const int4*)(src + idx);
            int4 d4 = *(const int4*)(dst + idx);
            int ss[4] = {s4.x, s4.y, s4.z, s4.w};
            int dd[4] = {d4.x, d4.y, d4.z, d4.w};
#pragma unroll
            for (int j = 0; j < 4; ++j) {
                int b = dd[j] >> SHIFT;
                bins[4 * k + j] = b;
                recs[4 * k + j] = ss[j] | ((dd[j] & (BNODES - 1)) << 17);
                atomicAdd(&hist[b], 1);
            }
        } else {
#pragma unroll
            for (int j = 0; j < 4; ++j) {
                int i2 = idx + j;
                if (i2 < e) {
                    int d = dst[i2];
                    int b = d >> SHIFT;
                    bins[4 * k + j] = b;
                    recs[4 * k + j] = src[i2] | ((d & (BNODES - 1)) << 17);
                    atomicAdd(&hist[b], 1);
                } else {
                    bins[4 * k + j] = -1;
                }
            }
        }
    }
    __syncthreads();

    cnt[t] = (t < NB) ? hist[t] : 0;
    __syncthreads();
    for (int off = 1; off < SB; off <<= 1) {
        int w = (t >= off) ? cnt[t - off] : 0;
        __syncthreads();
        cnt[t] += w;
        __syncthreads();
    }
    if (t < NB) {
        int excl = cnt[t] - hist[t];
        start[t] = excl;
        cnt[t] = excl;
        int c = hist[t];
        runbase[t] = c ? atomicAdd(&claim[t], c) : 0;
    }
    __syncthreads();

#pragma unroll
    for (int m = 0; m < 16; ++m) {
        int b = bins[m];
        if (b >= 0) {
            int pos = atomicAdd(&cnt[b], 1);
            stage[pos] = recs[m];
            binmap[pos] = (unsigned char)b;
        }
    }
    __syncthreads();

    for (int i = t; i < n; i += SB) {
        int b = binmap[i];
        sg[b * CAP + runbase[b] + (i - start[b])] = stage[i];
    }
}

// per bucket: counting-sort records by dst_local; emit beg/end + u = dinv*x
__global__ __launch_bounds__(1024) void k_refine(const int* __restrict__ claim,
                                                 const int* __restrict__ sg,
                                                 const float* __restrict__ x,
                                                 int* sg2, int* beg, int* endv,
                                                 float2* u) {
    __shared__ int hist[BNODES];
    __shared__ int excl[BNODES];
    const int t = threadIdx.x;
    const int b = blockIdx.x;
    if (t < BNODES) hist[t] = 0;
    __syncthreads();

    const int* p = sg + b * CAP;
    const int len = claim[b];
    const int tb = len & ~3;
    for (int i = 4 * t; i < tb; i += 4096) {
        int4 r = *(const int4*)(p + i);
        atomicAdd(&hist[((unsigned)r.x) >> 17], 1);
        atomicAdd(&hist[((unsigned)r.y) >> 17], 1);
        atomicAdd(&hist[((unsigned)r.z) >> 17], 1);
        atomicAdd(&hist[((unsigned)r.w) >> 17], 1);
    }
    if (t < len - tb) atomicAdd(&hist[((unsigned)p[tb + t]) >> 17], 1);
    __syncthreads();

    // inclusive scan over 512 counters (first 512 threads)
    if (t < BNODES) excl[t] = hist[t];
    __syncthreads();
    for (int off = 1; off < BNODES; off <<= 1) {
        int w = (t >= off && t < BNODES) ? excl[t - off] : 0;
        __syncthreads();
        if (t < BNODES) excl[t] += w;
        __syncthreads();
    }

    int myexcl = 0;
    if (t < BNODES) {
        int mycnt = hist[t];
        myexcl = excl[t] - mycnt;           // exclusive prefix
        int node = b * BNODES + t;
        if (node < N_NODES) {
            beg[node]  = b * CAP + myexcl;
            endv[node] = b * CAP + myexcl + mycnt;
            float dv = rsqrtf((float)(mycnt + 1));   // +1 self-loop
            float2 xv = ((const float2*)x)[node];
            u[node] = make_float2(dv * xv.x, dv * xv.y);
        }
    }
    __syncthreads();
    if (t < BNODES) hist[t] = myexcl;       // rank counters
    __syncthreads();

    int* q = sg2 + b * CAP;
    for (int i = 4 * t; i < tb; i += 4096) {
        int4 r = *(const int4*)(p + i);
        q[atomicAdd(&hist[((unsigned)r.x) >> 17], 1)] = r.x & 0x1FFFF;
        q[atomicAdd(&hist[((unsigned)r.y) >> 17], 1)] = r.y & 0x1FFFF;
        q[atomicAdd(&hist[((unsigned)r.z) >> 17], 1)] = r.z & 0x1FFFF;
        q[atomicAdd(&hist[((unsigned)r.w) >> 17], 1)] = r.w & 0x1FFFF;
    }
    if (t < len - tb) {
        int r = p[tb + t];
        q[atomicAdd(&hist[((unsigned)r) >> 17], 1)] = r & 0x1FFFF;
    }
}

// thread-per-node segment sum of u[src] (no atomics) + full 64-dim MLP
__global__ __launch_bounds__(256) void k_agg1(const int* __restrict__ sg2,
                                              const int* __restrict__ beg,
                                              const int* __restrict__ endv,
                                              const float2* __restrict__ u,
                                              const float* __restrict__ W1,
                                              const float* __restrict__ b1,
                                              const float* __restrict__ W2,
                                              float2* v) {
    __shared__ float sW1[128], sb1[64], sW2[128];
    int t = threadIdx.x;
    if (t < 128) { sW1[t] = W1[t]; sW2[t] = W2[t]; }
    else if (t < 192) sb1[t - 128] = b1[t - 128];
    __syncthreads();
    int n = blockIdx.x * 256 + t;
    if (n >= N_NODES) return;
    int s = beg[n], e2 = endv[n];
    float sx = 0.f, sy = 0.f;
    int i = s;
    for (; i + 4 <= e2; i += 4) {
        int r0 = sg2[i], r1 = sg2[i + 1], r2 = sg2[i + 2], r3 = sg2[i + 3];
        float2 g0 = u[r0], g1 = u[r1], g2 = u[r2], g3 = u[r3];
        sx += (g0.x + g1.x) + (g2.x + g3.x);
        sy += (g0.y + g1.y) + (g2.y + g3.y);
    }
    for (; i < e2; ++i) { float2 g = u[sg2[i]]; sx += g.x; sy += g.y; }
    float dv = rsqrtf((float)(e2 - s + 1));
    float2 un = u[n];
    float a0 = dv * (sx + un.x), a1 = dv * (sy + un.y);
    float y0 = 0.f, y1 = 0.f;
#pragma unroll
    for (int j = 0; j < 64; ++j) {
        float h = fmaxf(fmaf(sW1[2 * j], a0,
                        fmaf(sW1[2 * j + 1], a1, sb1[j])), 0.f);
        y0 = fmaf(sW2[j], h, y0);        // W2[0][j]
        y1 = fmaf(sW2[64 + j], h, y1);   // W2[1][j]
    }
    v[n] = make_float2(dv * y0, dv * y1);
}

// thread-per-node segment sum of v[src] + bias epilogue
__global__ __launch_bounds__(256) void k_agg2(const int* __restrict__ sg2,
                                              const int* __restrict__ beg,
                                              const int* __restrict__ endv,
                                              const float2* __restrict__ v,
                                              const float* __restrict__ b2,
                                              float2* out) {
    int n = blockIdx.x * 256 + threadIdx.x;
    if (n >= N_NODES) return;
    int s = beg[n], e2 = endv[n];
    float sx = 0.f, sy = 0.f;
    int i = s;
    for (; i + 4 <= e2; i += 4) {
        int r0 = sg2[i], r1 = sg2[i + 1], r2 = sg2[i + 2], r3 = sg2[i + 3];
        float2 g0 = v[r0], g1 = v[r1], g2 = v[r2], g3 = v[r3];
        sx += (g0.x + g1.x) + (g2.x + g3.x);
        sy += (g0.y + g1.y) + (g2.y + g3.y);
    }
    for (; i < e2; ++i) { float2 g = v[sg2[i]]; sx += g.x; sy += g.y; }
    float dv = rsqrtf((float)(e2 - s + 1));
    float2 vn = v[n];
    out[n] = make_float2(fmaf(dv, sx + vn.x, b2[0]),
                         fmaf(dv, sy + vn.y, b2[1]));
}

extern "C" void kernel_launch(void* const* d_in, const int* in_sizes, int n_in,
                              void* d_out, int out_size, void* d_ws, size_t ws_size,
                              hipStream_t stream) {
    const float* x  = (const float*)d_in[0];
    const int* ei   = (const int*)d_in[1];   // [2,E]: src row then dst row
    const float* W1 = (const float*)d_in[2];
    const float* b1 = (const float*)d_in[3];
    const float* W2 = (const float*)d_in[4];
    const float* b2 = (const float*)d_in[5];

    int e = in_sizes[1] / 2;
    const int* src = ei;
    const int* dst = ei + e;

    // ws layout (4B units): claim[196] | sg[NB*CAP] | sg2[NB*CAP] |
    //                       beg[N] | endv[N] | u[2N] | v[2N]
    int* ws      = (int*)d_ws;
    int* claim   = ws;
    int* sg      = ws + NB;                        // 196%4==0 -> 16B aligned
    int* sg2     = sg + NB * CAP;
    int* beg     = sg2 + NB * CAP;
    int* endv    = beg + N_NODES;
    float2* u    = (float2*)(endv + N_NODES);
    float2* v    = u + N_NODES;
    float2* outp = (float2*)d_out;

    hipMemsetAsync(claim, 0, NB * sizeof(int), stream);

    const int gN = (N_NODES + 255) / 256;
    k_sort  <<<(e + TILE - 1) / TILE, SB, 0, stream>>>(src, dst, claim, sg, e);
    k_refine<<<NB, 1024, 0, stream>>>(claim, sg, x, sg2, beg, endv, u);
    k_agg1  <<<gN, 256, 0, stream>>>(sg2, beg, endv, u, W1, b1, W2, v);
    k_agg2  <<<gN, 256, 0, stream>>>(sg2, beg, endv, v, b2, outp);
}

// Round 9
// 159.261 us; speedup vs baseline: 3.4151x; 1.0421x over previous
//
#include <hip/hip_runtime.h>

#define N_NODES 100000
#define SHIFT 9
#define BNODES 512                              // nodes per dst bucket
#define NB 196                                  // ceil(N_NODES/BNODES)
#define CAP 18432                               // slots/bucket; mean 16327, +16sigma; %4==0
#define TILE 8192                               // edges per sort block
#define SB 512                                  // sort block threads

// ---------------------------------------------------------------------------
// GCN 2-layer, algebraically refactored (aggregation in 2-dim feature space):
//   out = Â relu( (Â x) W1^T + b1 ) W2^T + b2 ,  Â = D^-1/2 (A+I) D^-1/2
// Two-level counting sort to full per-node order, then atomic-free
// thread-per-node segment sums fused with the register-resident 64-dim MLP.
// R9 deltas: sort tile 4096->8192 (longer coalesced runs, half the scan/claim
// overhead); refine caches its bucket in registers (one global pass, was two);
// per-node (beg,cnt) packed into one int32; agg gather unroll 4->8.
// Record: src (17b) | dst_local (9b) << 17.
// ---------------------------------------------------------------------------

__global__ __launch_bounds__(SB) void k_sort(const int* __restrict__ src,
                                             const int* __restrict__ dst,
                                             int* claim, int* sg, int e) {
    __shared__ int hist[NB];
    __shared__ int scanb[256];
    __shared__ int start[NB];               // tile-local exclusive starts
    __shared__ int runbase[NB];             // claimed global run base per bin
    __shared__ int stage[TILE];
    __shared__ unsigned char binmap[TILE];

    const int t = threadIdx.x;
    const int base = blockIdx.x * TILE;
    const int n = min(TILE, e - base);

    for (int i = t; i < NB; i += SB) hist[i] = 0;
    __syncthreads();

    int recs[16];
    int bins[16];
#pragma unroll
    for (int k = 0; k < 4; ++k) {
        int idx = base + (k * SB + t) * 4;
        if (idx + 3 < e) {
            int4 s4 = *(const int4*)(src + idx);
            int4 d4 = *(const int4*)(dst + idx);
            int ss[4] = {s4.x, s4.y, s4.z, s4.w};
            int dd[4] = {d4.x, d4.y, d4.z, d4.w};
#pragma unroll
            for (int j = 0; j < 4; ++j) {
                int b = dd[j] >> SHIFT;
                bins[4 * k + j] = b;
                recs[4 * k + j] = ss[j] | ((dd[j] & (BNODES - 1)) << 17);
                atomicAdd(&hist[b], 1);
            }
        } else {
#pragma unroll
            for (int j = 0; j < 4; ++j) {
                int i2 = idx + j;
                if (i2 < e) {
                    int d = dst[i2];
                    int b = d >> SHIFT;
                    bins[4 * k + j] = b;
                    recs[4 * k + j] = src[i2] | ((d & (BNODES - 1)) << 17);
                    atomicAdd(&hist[b], 1);
                } else {
                    bins[4 * k + j] = -1;
                }
            }
        }
    }
    __syncthreads();

    // scan of 196 bin counts over first 256 lanes
    if (t < 256) scanb[t] = (t < NB) ? hist[t] : 0;
    __syncthreads();
    for (int off = 1; off < 256; off <<= 1) {
        int w = (t < 256 && t >= off) ? scanb[t - off] : 0;
        __syncthreads();
        if (t < 256) scanb[t] += w;
        __syncthreads();
    }
    if (t < NB) {
        int c = hist[t];
        int excl = scanb[t] - c;
        start[t] = excl;
        scanb[t] = excl;                     // rank counters
        runbase[t] = c ? atomicAdd(&claim[t], c) : 0;
    }
    __syncthreads();

#pragma unroll
    for (int m = 0; m < 16; ++m) {
        int b = bins[m];
        if (b >= 0) {
            int pos = atomicAdd(&scanb[b], 1);
            stage[pos] = recs[m];
            binmap[pos] = (unsigned char)b;
        }
    }
    __syncthreads();

    // coalesced copy-out: consecutive staged slots -> consecutive run slots
    for (int i = t; i < n; i += SB) {
        int b = binmap[i];
        sg[b * CAP + runbase[b] + (i - start[b])] = stage[i];
    }
}

// per bucket: counting-sort by dst_local (records cached in registers),
// emit packed (beg | cnt<<22) + u = dinv*x
__global__ __launch_bounds__(1024) void k_refine(const int* __restrict__ claim,
                                                 const int* __restrict__ sg,
                                                 const float* __restrict__ x,
                                                 int* sg2, int* packed,
                                                 float2* u) {
    __shared__ int hist[BNODES];
    __shared__ int scanb[BNODES];
    const int t = threadIdx.x;
    const int b = blockIdx.x;
    const int* p = sg + b * CAP;
    const int len = claim[b];

    // one global pass: cache up to 20 records/thread (covers CAP=18432)
    int4 r[5];
#pragma unroll
    for (int k = 0; k < 5; ++k) {
        int idx = 4 * t + 4096 * k;
        int4 v = make_int4(-1, -1, -1, -1);
        if (idx + 3 < len) v = *(const int4*)(p + idx);
        else if (idx < len) {
            v.x = p[idx];
            if (idx + 1 < len) v.y = p[idx + 1];
            if (idx + 2 < len) v.z = p[idx + 2];
        }
        r[k] = v;
    }
    if (t < BNODES) hist[t] = 0;
    __syncthreads();
#pragma unroll
    for (int k = 0; k < 5; ++k) {
        if (r[k].x != -1) atomicAdd(&hist[((unsigned)r[k].x) >> 17], 1);
        if (r[k].y != -1) atomicAdd(&hist[((unsigned)r[k].y) >> 17], 1);
        if (r[k].z != -1) atomicAdd(&hist[((unsigned)r[k].z) >> 17], 1);
        if (r[k].w != -1) atomicAdd(&hist[((unsigned)r[k].w) >> 17], 1);
    }
    __syncthreads();

    if (t < BNODES) scanb[t] = hist[t];
    __syncthreads();
    for (int off = 1; off < BNODES; off <<= 1) {
        int w = (t >= off && t < BNODES) ? scanb[t - off] : 0;
        __syncthreads();
        if (t < BNODES) scanb[t] += w;
        __syncthreads();
    }
    if (t < BNODES) {
        int mycnt = hist[t];
        int myexcl = scanb[t] - mycnt;
        int node = b * BNODES + t;
        if (node < N_NODES) {
            packed[node] = (b * CAP + myexcl) | (mycnt << 22);
            float dv = rsqrtf((float)(mycnt + 1));   // +1 self-loop
            float2 xv = ((const float2*)x)[node];
            u[node] = make_float2(dv * xv.x, dv * xv.y);
        }
        hist[t] = myexcl;                    // rank counters
    }
    __syncthreads();

    int* q = sg2 + b * CAP;
#pragma unroll
    for (int k = 0; k < 5; ++k) {
        if (r[k].x != -1) q[atomicAdd(&hist[((unsigned)r[k].x) >> 17], 1)] = r[k].x & 0x1FFFF;
        if (r[k].y != -1) q[atomicAdd(&hist[((unsigned)r[k].y) >> 17], 1)] = r[k].y & 0x1FFFF;
        if (r[k].z != -1) q[atomicAdd(&hist[((unsigned)r[k].z) >> 17], 1)] = r[k].z & 0x1FFFF;
        if (r[k].w != -1) q[atomicAdd(&hist[((unsigned)r[k].w) >> 17], 1)] = r[k].w & 0x1FFFF;
    }
}

// thread-per-node segment sum of u[src] (no atomics) + full 64-dim MLP
__global__ __launch_bounds__(256) void k_agg1(const int* __restrict__ sg2,
                                              const int* __restrict__ packed,
                                              const float2* __restrict__ u,
                                              const float* __restrict__ W1,
                                              const float* __restrict__ b1,
                                              const float* __restrict__ W2,
                                              float2* v) {
    __shared__ float sW1[128], sb1[64], sW2[128];
    int t = threadIdx.x;
    if (t < 128) { sW1[t] = W1[t]; sW2[t] = W2[t]; }
    else if (t < 192) sb1[t - 128] = b1[t - 128];
    __syncthreads();
    int n = blockIdx.x * 256 + t;
    if (n >= N_NODES) return;
    int pk = packed[n];
    int s = pk & 0x3FFFFF;
    int cnt = ((unsigned)pk) >> 22;
    int e2 = s + cnt;
    float sx = 0.f, sy = 0.f;
    int i = s;
    for (; i + 8 <= e2; i += 8) {
        float2 g0 = u[sg2[i]],     g1 = u[sg2[i + 1]];
        float2 g2 = u[sg2[i + 2]], g3 = u[sg2[i + 3]];
        float2 g4 = u[sg2[i + 4]], g5 = u[sg2[i + 5]];
        float2 g6 = u[sg2[i + 6]], g7 = u[sg2[i + 7]];
        sx += ((g0.x + g1.x) + (g2.x + g3.x)) + ((g4.x + g5.x) + (g6.x + g7.x));
        sy += ((g0.y + g1.y) + (g2.y + g3.y)) + ((g4.y + g5.y) + (g6.y + g7.y));
    }
    for (; i < e2; ++i) { float2 g = u[sg2[i]]; sx += g.x; sy += g.y; }
    float dv = rsqrtf((float)(cnt + 1));
    float2 un = u[n];
    float a0 = dv * (sx + un.x), a1 = dv * (sy + un.y);
    float y0 = 0.f, y1 = 0.f;
#pragma unroll
    for (int j = 0; j < 64; ++j) {
        float h = fmaxf(fmaf(sW1[2 * j], a0,
                        fmaf(sW1[2 * j + 1], a1, sb1[j])), 0.f);
        y0 = fmaf(sW2[j], h, y0);        // W2[0][j]
        y1 = fmaf(sW2[64 + j], h, y1);   // W2[1][j]
    }
    v[n] = make_float2(dv * y0, dv * y1);
}

// thread-per-node segment sum of v[src] + bias epilogue
__global__ __launch_bounds__(256) void k_agg2(const int* __restrict__ sg2,
                                              const int* __restrict__ packed,
                                              const float2* __restrict__ v,
                                              const float* __restrict__ b2,
                                              float2* out) {
    int n = blockIdx.x * 256 + threadIdx.x;
    if (n >= N_NODES) return;
    int pk = packed[n];
    int s = pk & 0x3FFFFF;
    int cnt = ((unsigned)pk) >> 22;
    int e2 = s + cnt;
    float sx = 0.f, sy = 0.f;
    int i = s;
    for (; i + 8 <= e2; i += 8) {
        float2 g0 = v[sg2[i]],     g1 = v[sg2[i + 1]];
        float2 g2 = v[sg2[i + 2]], g3 = v[sg2[i + 3]];
        float2 g4 = v[sg2[i + 4]], g5 = v[sg2[i + 5]];
        float2 g6 = v[sg2[i + 6]], g7 = v[sg2[i + 7]];
        sx += ((g0.x + g1.x) + (g2.x + g3.x)) + ((g4.x + g5.x) + (g6.x + g7.x));
        sy += ((g0.y + g1.y) + (g2.y + g3.y)) + ((g4.y + g5.y) + (g6.y + g7.y));
    }
    for (; i < e2; ++i) { float2 g = v[sg2[i]]; sx += g.x; sy += g.y; }
    float dv = rsqrtf((float)(cnt + 1));
    float2 vn = v[n];
    out[n] = make_float2(fmaf(dv, sx + vn.x, b2[0]),
                         fmaf(dv, sy + vn.y, b2[1]));
}

extern "C" void kernel_launch(void* const* d_in, const int* in_sizes, int n_in,
                              void* d_out, int out_size, void* d_ws, size_t ws_size,
                              hipStream_t stream) {
    const float* x  = (const float*)d_in[0];
    const int* ei   = (const int*)d_in[1];   // [2,E]: src row then dst row
    const float* W1 = (const float*)d_in[2];
    const float* b1 = (const float*)d_in[3];
    const float* W2 = (const float*)d_in[4];
    const float* b2 = (const float*)d_in[5];

    int e = in_sizes[1] / 2;
    const int* src = ei;
    const int* dst = ei + e;

    // ws layout (4B units): claim[196] | sg[NB*CAP] | sg2[NB*CAP] |
    //                       packed[N] | u[2N] | v[2N]
    int* ws      = (int*)d_ws;
    int* claim   = ws;
    int* sg      = ws + NB;                        // 196%4==0 -> 16B aligned
    int* sg2     = sg + NB * CAP;
    int* packed  = sg2 + NB * CAP;
    float2* u    = (float2*)(packed + N_NODES);
    float2* v    = u + N_NODES;
    float2* outp = (float2*)d_out;

    hipMemsetAsync(claim, 0, NB * sizeof(int), stream);

    const int gN = (N_NODES + 255) / 256;
    k_sort  <<<(e + TILE - 1) / TILE, SB, 0, stream>>>(src, dst, claim, sg, e);
    k_refine<<<NB, 1024, 0, stream>>>(claim, sg, x, sg2, packed, u);
    k_agg1  <<<gN, 256, 0, stream>>>(sg2, packed, u, W1, b1, W2, v);
    k_agg2  <<<gN, 256, 0, stream>>>(sg2, packed, v, b2, outp);
}

// Round 10
// 153.702 us; speedup vs baseline: 3.5386x; 1.0362x over previous
//
#include <hip/hip_runtime.h>

#define N_NODES 100000
#define SHIFT 9
#define BNODES 512                              // nodes per dst bucket
#define NB 196                                  // ceil(N_NODES/BNODES)
#define CAP 18432                               // slots/bucket; mean 16384, +16sigma; %4==0
#define TILE 8192                               // edges per sort block
#define SB 512                                  // sort block threads

// ---------------------------------------------------------------------------
// GCN 2-layer, algebraically refactored (aggregation in 2-dim feature space):
//   out = Â relu( (Â x) W1^T + b1 ) W2^T + b2 ,  Â = D^-1/2 (A+I) D^-1/2
// Two-level counting sort to full per-node order, then atomic-free segment
// sums. R10 delta: aggs were parallelism-starved (thread-per-node = 6
// waves/CU vs ~200cyc L2-hit gathers). Now 8 LANES PER NODE: coalesced sg2
// reads, shfl_xor(width=8) tree reduction, 64-dim MLP split 8 units/lane ->
// 48 waves/CU, 8x outstanding gathers.
// Record: src (17b) | dst_local (9b) << 17.  packed: beg | cnt<<22.
// ---------------------------------------------------------------------------

__global__ __launch_bounds__(SB) void k_sort(const int* __restrict__ src,
                                             const int* __restrict__ dst,
                                             int* claim, int* sg, int e) {
    __shared__ int hist[NB];
    __shared__ int scanb[256];
    __shared__ int start[NB];               // tile-local exclusive starts
    __shared__ int runbase[NB];             // claimed global run base per bin
    __shared__ int stage[TILE];
    __shared__ unsigned char binmap[TILE];

    const int t = threadIdx.x;
    const int base = blockIdx.x * TILE;
    const int n = min(TILE, e - base);

    for (int i = t; i < NB; i += SB) hist[i] = 0;
    __syncthreads();

    int recs[16];
    int bins[16];
#pragma unroll
    for (int k = 0; k < 4; ++k) {
        int idx = base + (k * SB + t) * 4;
        if (idx + 3 < e) {
            int4 s4 = *(const int4*)(src + idx);
            int4 d4 = *(const int4*)(dst + idx);
            int ss[4] = {s4.x, s4.y, s4.z, s4.w};
            int dd[4] = {d4.x, d4.y, d4.z, d4.w};
#pragma unroll
            for (int j = 0; j < 4; ++j) {
                int b = dd[j] >> SHIFT;
                bins[4 * k + j] = b;
                recs[4 * k + j] = ss[j] | ((dd[j] & (BNODES - 1)) << 17);
                atomicAdd(&hist[b], 1);
            }
        } else {
#pragma unroll
            for (int j = 0; j < 4; ++j) {
                int i2 = idx + j;
                if (i2 < e) {
                    int d = dst[i2];
                    int b = d >> SHIFT;
                    bins[4 * k + j] = b;
                    recs[4 * k + j] = src[i2] | ((d & (BNODES - 1)) << 17);
                    atomicAdd(&hist[b], 1);
                } else {
                    bins[4 * k + j] = -1;
                }
            }
        }
    }
    __syncthreads();

    if (t < 256) scanb[t] = (t < NB) ? hist[t] : 0;
    __syncthreads();
    for (int off = 1; off < 256; off <<= 1) {
        int w = (t < 256 && t >= off) ? scanb[t - off] : 0;
        __syncthreads();
        if (t < 256) scanb[t] += w;
        __syncthreads();
    }
    if (t < NB) {
        int c = hist[t];
        int excl = scanb[t] - c;
        start[t] = excl;
        scanb[t] = excl;                     // rank counters
        runbase[t] = c ? atomicAdd(&claim[t], c) : 0;
    }
    __syncthreads();

#pragma unroll
    for (int m = 0; m < 16; ++m) {
        int b = bins[m];
        if (b >= 0) {
            int pos = atomicAdd(&scanb[b], 1);
            stage[pos] = recs[m];
            binmap[pos] = (unsigned char)b;
        }
    }
    __syncthreads();

    for (int i = t; i < n; i += SB) {
        int b = binmap[i];
        sg[b * CAP + runbase[b] + (i - start[b])] = stage[i];
    }
}

// per bucket: counting-sort by dst_local (records cached in registers),
// emit packed (beg | cnt<<22) + u = dinv*x
__global__ __launch_bounds__(1024) void k_refine(const int* __restrict__ claim,
                                                 const int* __restrict__ sg,
                                                 const float* __restrict__ x,
                                                 int* sg2, int* packed,
                                                 float2* u) {
    __shared__ int hist[BNODES];
    __shared__ int scanb[BNODES];
    const int t = threadIdx.x;
    const int b = blockIdx.x;
    const int* p = sg + b * CAP;
    const int len = claim[b];

    int4 r[5];
#pragma unroll
    for (int k = 0; k < 5; ++k) {
        int idx = 4 * t + 4096 * k;
        int4 v = make_int4(-1, -1, -1, -1);
        if (idx + 3 < len) v = *(const int4*)(p + idx);
        else if (idx < len) {
            v.x = p[idx];
            if (idx + 1 < len) v.y = p[idx + 1];
            if (idx + 2 < len) v.z = p[idx + 2];
        }
        r[k] = v;
    }
    if (t < BNODES) hist[t] = 0;
    __syncthreads();
#pragma unroll
    for (int k = 0; k < 5; ++k) {
        if (r[k].x != -1) atomicAdd(&hist[((unsigned)r[k].x) >> 17], 1);
        if (r[k].y != -1) atomicAdd(&hist[((unsigned)r[k].y) >> 17], 1);
        if (r[k].z != -1) atomicAdd(&hist[((unsigned)r[k].z) >> 17], 1);
        if (r[k].w != -1) atomicAdd(&hist[((unsigned)r[k].w) >> 17], 1);
    }
    __syncthreads();

    if (t < BNODES) scanb[t] = hist[t];
    __syncthreads();
    for (int off = 1; off < BNODES; off <<= 1) {
        int w = (t >= off && t < BNODES) ? scanb[t - off] : 0;
        __syncthreads();
        if (t < BNODES) scanb[t] += w;
        __syncthreads();
    }
    if (t < BNODES) {
        int mycnt = hist[t];
        int myexcl = scanb[t] - mycnt;
        int node = b * BNODES + t;
        if (node < N_NODES) {
            packed[node] = (b * CAP + myexcl) | (mycnt << 22);
            float dv = rsqrtf((float)(mycnt + 1));   // +1 self-loop
            float2 xv = ((const float2*)x)[node];
            u[node] = make_float2(dv * xv.x, dv * xv.y);
        }
        hist[t] = myexcl;                    // rank counters
    }
    __syncthreads();

    int* q = sg2 + b * CAP;
#pragma unroll
    for (int k = 0; k < 5; ++k) {
        if (r[k].x != -1) q[atomicAdd(&hist[((unsigned)r[k].x) >> 17], 1)] = r[k].x & 0x1FFFF;
        if (r[k].y != -1) q[atomicAdd(&hist[((unsigned)r[k].y) >> 17], 1)] = r[k].y & 0x1FFFF;
        if (r[k].z != -1) q[atomicAdd(&hist[((unsigned)r[k].z) >> 17], 1)] = r[k].z & 0x1FFFF;
        if (r[k].w != -1) q[atomicAdd(&hist[((unsigned)r[k].w) >> 17], 1)] = r[k].w & 0x1FFFF;
    }
}

// 8 lanes per node: coalesced segment gather-sum of u[src], shfl_xor
// reduction, 64-dim MLP split 8 hidden units/lane, reduce, lane0 stores v.
__global__ __launch_bounds__(256) void k_agg1(const int* __restrict__ sg2,
                                              const int* __restrict__ packed,
                                              const float2* __restrict__ u,
                                              const float* __restrict__ W1,
                                              const float* __restrict__ b1,
                                              const float* __restrict__ W2,
                                              float2* v) {
    __shared__ float sW1[128], sb1[64], sW2[128];
    int t = threadIdx.x;
    if (t < 128) { sW1[t] = W1[t]; sW2[t] = W2[t]; }
    else if (t < 192) sb1[t - 128] = b1[t - 128];
    __syncthreads();
    int n = blockIdx.x * 32 + (t >> 3);
    if (n >= N_NODES) return;
    int g = t & 7;
    int pk = packed[n];
    int s = pk & 0x3FFFFF;
    int cnt = ((unsigned)pk) >> 22;
    int e2 = s + cnt;
    float sx = 0.f, sy = 0.f;
    int i = s + g;
    for (; i + 8 < e2; i += 16) {            // two independent gathers/iter
        float2 ga = u[sg2[i]];
        float2 gb = u[sg2[i + 8]];
        sx += ga.x + gb.x;
        sy += ga.y + gb.y;
    }
    if (i < e2) { float2 ga = u[sg2[i]]; sx += ga.x; sy += ga.y; }
    sx += __shfl_xor(sx, 1, 8); sy += __shfl_xor(sy, 1, 8);
    sx += __shfl_xor(sx, 2, 8); sy += __shfl_xor(sy, 2, 8);
    sx += __shfl_xor(sx, 4, 8); sy += __shfl_xor(sy, 4, 8);
    float dv = rsqrtf((float)(cnt + 1));
    float2 un = u[n];
    float a0 = dv * (sx + un.x), a1 = dv * (sy + un.y);
    float y0 = 0.f, y1 = 0.f;
#pragma unroll
    for (int k = 0; k < 8; ++k) {            // 8 hidden units per lane
        int j = g + 8 * k;
        float h = fmaxf(fmaf(sW1[2 * j], a0,
                        fmaf(sW1[2 * j + 1], a1, sb1[j])), 0.f);
        y0 = fmaf(sW2[j], h, y0);            // W2[0][j]
        y1 = fmaf(sW2[64 + j], h, y1);       // W2[1][j]
    }
    y0 += __shfl_xor(y0, 1, 8); y1 += __shfl_xor(y1, 1, 8);
    y0 += __shfl_xor(y0, 2, 8); y1 += __shfl_xor(y1, 2, 8);
    y0 += __shfl_xor(y0, 4, 8); y1 += __shfl_xor(y1, 4, 8);
    if (g == 0) v[n] = make_float2(dv * y0, dv * y1);
}

// 8 lanes per node: segment sum of v[src] + bias epilogue
__global__ __launch_bounds__(256) void k_agg2(const int* __restrict__ sg2,
                                              const int* __restrict__ packed,
                                              const float2* __restrict__ v,
                                              const float* __restrict__ b2,
                                              float2* out) {
    int t = threadIdx.x;
    int n = blockIdx.x * 32 + (t >> 3);
    if (n >= N_NODES) return;
    int g = t & 7;
    int pk = packed[n];
    int s = pk & 0x3FFFFF;
    int cnt = ((unsigned)pk) >> 22;
    int e2 = s + cnt;
    float sx = 0.f, sy = 0.f;
    int i = s + g;
    for (; i + 8 < e2; i += 16) {
        float2 ga = v[sg2[i]];
        float2 gb = v[sg2[i + 8]];
        sx += ga.x + gb.x;
        sy += ga.y + gb.y;
    }
    if (i < e2) { float2 ga = v[sg2[i]]; sx += ga.x; sy += ga.y; }
    sx += __shfl_xor(sx, 1, 8); sy += __shfl_xor(sy, 1, 8);
    sx += __shfl_xor(sx, 2, 8); sy += __shfl_xor(sy, 2, 8);
    sx += __shfl_xor(sx, 4, 8); sy += __shfl_xor(sy, 4, 8);
    if (g == 0) {
        float dv = rsqrtf((float)(cnt + 1));
        float2 vn = v[n];
        out[n] = make_float2(fmaf(dv, sx + vn.x, b2[0]),
                             fmaf(dv, sy + vn.y, b2[1]));
    }
}

extern "C" void kernel_launch(void* const* d_in, const int* in_sizes, int n_in,
                              void* d_out, int out_size, void* d_ws, size_t ws_size,
                              hipStream_t stream) {
    const float* x  = (const float*)d_in[0];
    const int* ei   = (const int*)d_in[1];   // [2,E]: src row then dst row
    const float* W1 = (const float*)d_in[2];
    const float* b1 = (const float*)d_in[3];
    const float* W2 = (const float*)d_in[4];
    const float* b2 = (const float*)d_in[5];

    int e = in_sizes[1] / 2;
    const int* src = ei;
    const int* dst = ei + e;

    // ws layout (4B units): claim[196] | sg[NB*CAP] | sg2[NB*CAP] |
    //                       packed[N] | u[2N] | v[2N]
    int* ws      = (int*)d_ws;
    int* claim   = ws;
    int* sg      = ws + NB;                        // 196%4==0 -> 16B aligned
    int* sg2     = sg + NB * CAP;
    int* packed  = sg2 + NB * CAP;
    float2* u    = (float2*)(packed + N_NODES);
    float2* v    = u + N_NODES;
    float2* outp = (float2*)d_out;

    hipMemsetAsync(claim, 0, NB * sizeof(int), stream);

    const int gA = (N_NODES + 31) / 32;            // 8 lanes/node, 32 nodes/block
    k_sort  <<<(e + TILE - 1) / TILE, SB, 0, stream>>>(src, dst, claim, sg, e);
    k_refine<<<NB, 1024, 0, stream>>>(claim, sg, x, sg2, packed, u);
    k_agg1  <<<gA, 256, 0, stream>>>(sg2, packed, u, W1, b1, W2, v);
    k_agg2  <<<gA, 256, 0, stream>>>(sg2, packed, v, b2, outp);
}

// Round 11
// 152.313 us; speedup vs baseline: 3.5708x; 1.0091x over previous
//
#include <hip/hip_runtime.h>

#define N_NODES 100000
#define SHIFT 8
#define BNODES 256                              // nodes per dst bucket
#define NB 391                                  // ceil(N_NODES/BNODES)
#define CAP 9728                                // slots/bucket; mean 8192, +17sigma; %4==0
#define TILE 8192                               // edges per sort block
#define SB 512                                  // sort block threads

// ---------------------------------------------------------------------------
// GCN 2-layer, algebraically refactored (aggregation in 2-dim feature space):
//   out = Â relu( (Â x) W1^T + b1 ) W2^T + b2 ,  Â = D^-1/2 (A+I) D^-1/2
// Two-level counting sort to full per-node order, then atomic-free segment
// sums (8 lanes/node) fused with the register-resident 64-dim MLP.
// R11 deltas: BNODES 512->256 (refine grid 196->391 blocks, 1.5 blocks/CU);
// shfl-based scans (2 syncthreads instead of 18); replicated LDS hists with
// per-group rank bases (2x sort / 4x refine less atomic contention); combined
// addrbase word in sort copy-out; agg gather ILP 2->4.
// Record: src (17b) | dst_local (8b) << 17.  packed: beg (22b) | cnt<<22.
// ---------------------------------------------------------------------------

__global__ __launch_bounds__(SB) void k_sort(const int* __restrict__ src,
                                             const int* __restrict__ dst,
                                             int* claim, int* sg, int e) {
    __shared__ int hist[2 * NB];            // 2 count replicas
    __shared__ int rank[2 * NB];            // 2 rank-counter groups
    __shared__ int addrbase[NB];            // b*CAP + runbase - excl
    __shared__ int partials[8];
    __shared__ int stage[TILE];
    __shared__ unsigned short binmap[TILE];

    const int t = threadIdx.x;
    const int base = blockIdx.x * TILE;
    const int n = min(TILE, e - base);
    const int goff = (t >> 8) * NB;         // replica group (0 or 1)

    for (int i = t; i < 2 * NB; i += SB) hist[i] = 0;
    __syncthreads();

    int recs[16];
    int bins[16];
    int* myh = hist + goff;
#pragma unroll
    for (int k = 0; k < 4; ++k) {
        int idx = base + (k * SB + t) * 4;
        if (idx + 3 < e) {
            int4 s4 = *(const int4*)(src + idx);
            int4 d4 = *(const int4*)(dst + idx);
            int ss[4] = {s4.x, s4.y, s4.z, s4.w};
            int dd[4] = {d4.x, d4.y, d4.z, d4.w};
#pragma unroll
            for (int j = 0; j < 4; ++j) {
                int b = dd[j] >> SHIFT;
                bins[4 * k + j] = b;
                recs[4 * k + j] = ss[j] | ((dd[j] & (BNODES - 1)) << 17);
                atomicAdd(&myh[b], 1);
            }
        } else {
#pragma unroll
            for (int j = 0; j < 4; ++j) {
                int i2 = idx + j;
                if (i2 < e) {
                    int d = dst[i2];
                    int b = d >> SHIFT;
                    bins[4 * k + j] = b;
                    recs[4 * k + j] = src[i2] | ((d & (BNODES - 1)) << 17);
                    atomicAdd(&myh[b], 1);
                } else {
                    bins[4 * k + j] = -1;
                }
            }
        }
    }
    __syncthreads();

    // shfl-based inclusive scan of per-bin totals over 512 threads (8 waves)
    int c0 = (t < NB) ? hist[t] : 0;
    int c = c0 + ((t < NB) ? hist[NB + t] : 0);
    int vs = c;
#pragma unroll
    for (int off = 1; off < 64; off <<= 1) {
        int w = __shfl_up(vs, off, 64);
        if ((t & 63) >= off) vs += w;
    }
    if ((t & 63) == 63) partials[t >> 6] = vs;
    __syncthreads();
    int add = 0;
    for (int w = 0; w < (t >> 6); ++w) add += partials[w];
    vs += add;
    int excl = vs - c;
    if (t < NB) {
        rank[t] = excl;                      // group-0 rank base
        rank[NB + t] = excl + c0;            // group-1 rank base
        int rb = c ? atomicAdd(&claim[t], c) : 0;
        addrbase[t] = t * CAP + rb - excl;
    }
    __syncthreads();

#pragma unroll
    for (int m = 0; m < 16; ++m) {
        int b = bins[m];
        if (b >= 0) {
            int pos = atomicAdd(&rank[goff + b], 1);
            stage[pos] = recs[m];
            binmap[pos] = (unsigned short)b;
        }
    }
    __syncthreads();

    // coalesced copy-out: consecutive staged slots -> consecutive run slots
    for (int i = t; i < n; i += SB) {
        sg[addrbase[binmap[i]] + i] = stage[i];
    }
}

// per bucket: counting-sort by dst_local (records cached in registers, one
// global pass); 4 hist replicas + per-group rank bases; emit packed + u
__global__ __launch_bounds__(1024) void k_refine(const int* __restrict__ claim,
                                                 const int* __restrict__ sg,
                                                 const float* __restrict__ x,
                                                 int* sg2, int* packed,
                                                 float2* u) {
    __shared__ int hist[4 * BNODES];
    __shared__ int rank[4 * BNODES];
    __shared__ int partials[4];
    const int t = threadIdx.x;
    const int b = blockIdx.x;
    const int* p = sg + b * CAP;
    const int len = claim[b];
    const int g = t >> 8;                   // replica group 0..3

    int4 r[3];
#pragma unroll
    for (int k = 0; k < 3; ++k) {
        int idx = 4 * t + 4096 * k;
        int4 v = make_int4(-1, -1, -1, -1);
        if (idx + 3 < len) v = *(const int4*)(p + idx);
        else if (idx < len) {
            v.x = p[idx];
            if (idx + 1 < len) v.y = p[idx + 1];
            if (idx + 2 < len) v.z = p[idx + 2];
        }
        r[k] = v;
    }
    for (int i = t; i < 4 * BNODES; i += 1024) hist[i] = 0;
    __syncthreads();
    int* myh = hist + g * BNODES;
#pragma unroll
    for (int k = 0; k < 3; ++k) {
        if (r[k].x != -1) atomicAdd(&myh[((unsigned)r[k].x) >> 17], 1);
        if (r[k].y != -1) atomicAdd(&myh[((unsigned)r[k].y) >> 17], 1);
        if (r[k].z != -1) atomicAdd(&myh[((unsigned)r[k].z) >> 17], 1);
        if (r[k].w != -1) atomicAdd(&myh[((unsigned)r[k].w) >> 17], 1);
    }
    __syncthreads();

    // shfl scan of per-node totals over first 256 threads (4 waves)
    int c4x = 0, c4y = 0, c4z = 0, c4w = 0, tot = 0;
    if (t < BNODES) {
        c4x = hist[t];
        c4y = hist[BNODES + t];
        c4z = hist[2 * BNODES + t];
        c4w = hist[3 * BNODES + t];
        tot = (c4x + c4y) + (c4z + c4w);
    }
    int vs = tot;
#pragma unroll
    for (int off = 1; off < 64; off <<= 1) {
        int w = __shfl_up(vs, off, 64);
        if ((t & 63) >= off) vs += w;
    }
    if ((t & 63) == 63 && t < BNODES) partials[t >> 6] = vs;
    __syncthreads();
    if (t < BNODES) {
        int add = 0;
        for (int w = 0; w < (t >> 6); ++w) add += partials[w];
        vs += add;
        int excl = vs - tot;
        int run = excl;
        rank[t] = run; run += c4x;
        rank[BNODES + t] = run; run += c4y;
        rank[2 * BNODES + t] = run; run += c4z;
        rank[3 * BNODES + t] = run;
        int node = b * BNODES + t;
        if (node < N_NODES) {
            packed[node] = (b * CAP + excl) | (tot << 22);
            float dv = rsqrtf((float)(tot + 1));     // +1 self-loop
            float2 xv = ((const float2*)x)[node];
            u[node] = make_float2(dv * xv.x, dv * xv.y);
        }
    }
    __syncthreads();

    int* q = sg2 + b * CAP;
    int* myr = rank + g * BNODES;
#pragma unroll
    for (int k = 0; k < 3; ++k) {
        if (r[k].x != -1) q[atomicAdd(&myr[((unsigned)r[k].x) >> 17], 1)] = r[k].x & 0x1FFFF;
        if (r[k].y != -1) q[atomicAdd(&myr[((unsigned)r[k].y) >> 17], 1)] = r[k].y & 0x1FFFF;
        if (r[k].z != -1) q[atomicAdd(&myr[((unsigned)r[k].z) >> 17], 1)] = r[k].z & 0x1FFFF;
        if (r[k].w != -1) q[atomicAdd(&myr[((unsigned)r[k].w) >> 17], 1)] = r[k].w & 0x1FFFF;
    }
}

// 8 lanes per node: coalesced segment gather-sum of u[src] (4 gathers in
// flight), shfl_xor reduction, 64-dim MLP split 8 units/lane, lane0 stores v.
__global__ __launch_bounds__(256) void k_agg1(const int* __restrict__ sg2,
                                              const int* __restrict__ packed,
                                              const float2* __restrict__ u,
                                              const float* __restrict__ W1,
                                              const float* __restrict__ b1,
                                              const float* __restrict__ W2,
                                              float2* v) {
    __shared__ float sW1[128], sb1[64], sW2[128];
    int t = threadIdx.x;
    if (t < 128) { sW1[t] = W1[t]; sW2[t] = W2[t]; }
    else if (t < 192) sb1[t - 128] = b1[t - 128];
    __syncthreads();
    int n = blockIdx.x * 32 + (t >> 3);
    if (n >= N_NODES) return;
    int g = t & 7;
    int pk = packed[n];
    int s = pk & 0x3FFFFF;
    int cnt = ((unsigned)pk) >> 22;
    int e2 = s + cnt;
    float sx = 0.f, sy = 0.f;
    int i = s + g;
    for (; i + 24 < e2; i += 32) {           // 4 independent gathers in flight
        float2 ga = u[sg2[i]];
        float2 gb = u[sg2[i + 8]];
        float2 gc = u[sg2[i + 16]];
        float2 gd = u[sg2[i + 24]];
        sx += (ga.x + gb.x) + (gc.x + gd.x);
        sy += (ga.y + gb.y) + (gc.y + gd.y);
    }
    for (; i + 8 < e2; i += 16) {
        float2 ga = u[sg2[i]];
        float2 gb = u[sg2[i + 8]];
        sx += ga.x + gb.x;
        sy += ga.y + gb.y;
    }
    if (i < e2) { float2 ga = u[sg2[i]]; sx += ga.x; sy += ga.y; }
    sx += __shfl_xor(sx, 1, 8); sy += __shfl_xor(sy, 1, 8);
    sx += __shfl_xor(sx, 2, 8); sy += __shfl_xor(sy, 2, 8);
    sx += __shfl_xor(sx, 4, 8); sy += __shfl_xor(sy, 4, 8);
    float dv = rsqrtf((float)(cnt + 1));
    float2 un = u[n];
    float a0 = dv * (sx + un.x), a1 = dv * (sy + un.y);
    float y0 = 0.f, y1 = 0.f;
#pragma unroll
    for (int k = 0; k < 8; ++k) {            // 8 hidden units per lane
        int j = g + 8 * k;
        float h = fmaxf(fmaf(sW1[2 * j], a0,
                        fmaf(sW1[2 * j + 1], a1, sb1[j])), 0.f);
        y0 = fmaf(sW2[j], h, y0);            // W2[0][j]
        y1 = fmaf(sW2[64 + j], h, y1);       // W2[1][j]
    }
    y0 += __shfl_xor(y0, 1, 8); y1 += __shfl_xor(y1, 1, 8);
    y0 += __shfl_xor(y0, 2, 8); y1 += __shfl_xor(y1, 2, 8);
    y0 += __shfl_xor(y0, 4, 8); y1 += __shfl_xor(y1, 4, 8);
    if (g == 0) v[n] = make_float2(dv * y0, dv * y1);
}

// 8 lanes per node: segment sum of v[src] + bias epilogue
__global__ __launch_bounds__(256) void k_agg2(const int* __restrict__ sg2,
                                              const int* __restrict__ packed,
                                              const float2* __restrict__ v,
                                              const float* __restrict__ b2,
                                              float2* out) {
    int t = threadIdx.x;
    int n = blockIdx.x * 32 + (t >> 3);
    if (n >= N_NODES) return;
    int g = t & 7;
    int pk = packed[n];
    int s = pk & 0x3FFFFF;
    int cnt = ((unsigned)pk) >> 22;
    int e2 = s + cnt;
    float sx = 0.f, sy = 0.f;
    int i = s + g;
    for (; i + 24 < e2; i += 32) {
        float2 ga = v[sg2[i]];
        float2 gb = v[sg2[i + 8]];
        float2 gc = v[sg2[i + 16]];
        float2 gd = v[sg2[i + 24]];
        sx += (ga.x + gb.x) + (gc.x + gd.x);
        sy += (ga.y + gb.y) + (gc.y + gd.y);
    }
    for (; i + 8 < e2; i += 16) {
        float2 ga = v[sg2[i]];
        float2 gb = v[sg2[i + 8]];
        sx += ga.x + gb.x;
        sy += ga.y + gb.y;
    }
    if (i < e2) { float2 ga = v[sg2[i]]; sx += ga.x; sy += ga.y; }
    sx += __shfl_xor(sx, 1, 8); sy += __shfl_xor(sy, 1, 8);
    sx += __shfl_xor(sx, 2, 8); sy += __shfl_xor(sy, 2, 8);
    sx += __shfl_xor(sx, 4, 8); sy += __shfl_xor(sy, 4, 8);
    if (g == 0) {
        float dv = rsqrtf((float)(cnt + 1));
        float2 vn = v[n];
        out[n] = make_float2(fmaf(dv, sx + vn.x, b2[0]),
                             fmaf(dv, sy + vn.y, b2[1]));
    }
}

extern "C" void kernel_launch(void* const* d_in, const int* in_sizes, int n_in,
                              void* d_out, int out_size, void* d_ws, size_t ws_size,
                              hipStream_t stream) {
    const float* x  = (const float*)d_in[0];
    const int* ei   = (const int*)d_in[1];   // [2,E]: src row then dst row
    const float* W1 = (const float*)d_in[2];
    const float* b1 = (const float*)d_in[3];
    const float* W2 = (const float*)d_in[4];
    const float* b2 = (const float*)d_in[5];

    int e = in_sizes[1] / 2;
    const int* src = ei;
    const int* dst = ei + e;

    // ws layout (4B units): claim[NB] pad to 392 | sg[NB*CAP] | sg2[NB*CAP] |
    //                       packed[N] | u[2N] | v[2N]
    int* ws      = (int*)d_ws;
    int* claim   = ws;
    int* sg      = ws + ((NB + 3) & ~3);           // 16B-aligned
    int* sg2     = sg + NB * CAP;
    int* packed  = sg2 + NB * CAP;
    float2* u    = (float2*)(packed + N_NODES);
    float2* v    = u + N_NODES;
    float2* outp = (float2*)d_out;

    hipMemsetAsync(claim, 0, NB * sizeof(int), stream);

    const int gA = (N_NODES + 31) / 32;            // 8 lanes/node, 32 nodes/block
    k_sort  <<<(e + TILE - 1) / TILE, SB, 0, stream>>>(src, dst, claim, sg, e);
    k_refine<<<NB, 1024, 0, stream>>>(claim, sg, x, sg2, packed, u);
    k_agg1  <<<gA, 256, 0, stream>>>(sg2, packed, u, W1, b1, W2, v);
    k_agg2  <<<gA, 256, 0, stream>>>(sg2, packed, v, b2, outp);
}